// Round 11
// baseline (296.177 us; speedup 1.0000x reference)
//
#include <hip/hip_runtime.h>
#include <cstddef>

// Problem constants (fixed by setup_inputs)
#define BB 4
#define QQ 4096
#define MM 8
#define NN 21760

typedef __bf16 bf16_8 __attribute__((ext_vector_type(8)));
typedef __bf16 bf16_4 __attribute__((ext_vector_type(4)));
typedef float  floatx4 __attribute__((ext_vector_type(4)));

// ---------------------------------------------------------------------------
// Weight prep: fp32 W[K][N] -> bf16 Wt[N][K]  (round-3 verified layout).
// Wt: Wval[256x256] | Wq[384x256] (attn 0..127 | off 128..383) | Wout[256x256]
// biasq[384] = [b_attn | b_off] fp32.
// ---------------------------------------------------------------------------
__global__ __launch_bounds__(256) void prep_weights(
    const float* __restrict__ Wv, const float* __restrict__ Wa,
    const float* __restrict__ Wo, const float* __restrict__ Wu,
    const float* __restrict__ ba, const float* __restrict__ bo,
    __bf16* __restrict__ Wt, float* __restrict__ biasq)
{
    const int gid = blockIdx.x * 256 + threadIdx.x;
    if (gid < 65536) {
        const int n = gid >> 8, k = gid & 255;
        Wt[gid] = (__bf16)Wv[k * 256 + n];
    } else if (gid < 163840) {
        const int o = gid - 65536;
        const int n = o >> 8, k = o & 255;
        Wt[gid] = (__bf16)(n < 128 ? Wa[k * 128 + n] : Wo[k * 256 + (n - 128)]);
    } else if (gid < 229376) {
        const int o = gid - 163840;
        const int n = o >> 8, k = o & 255;
        Wt[gid] = (__bf16)Wu[k * 256 + n];
    } else if (gid < 229760) {
        const int j = gid - 229376;
        biasq[j] = (j < 128) ? ba[j] : bo[j - 128];
    }
}

// ---------------------------------------------------------------------------
// Pipelined v_p + q-proj GEMM (T3/T4 minimum recipe, plain HIP + 2 asm waits).
// Each block owns 128 tokens = 2 tiles x 2 K-halves = 4 phases, double-
// buffered 32 KB LDS.  Phase p steady state:
//   compute(p) reads As[p&1]; next-phase data was ds-written and barrier'd;
//   loads for phase p+2 are ALREADY IN FLIGHT (issued one phase ago) and
//   land during compute — the raw s_barrier does NOT drain vmcnt (unlike
//   __syncthreads), which is exactly what rounds 0-10's structures lost.
// Weights are loaded ONCE per block (halved weight traffic vs round 10).
// Blocks 0..383: q-proj (2 tiles each, 768 total; same slice per pair).
// Blocks 384..1063: v_p (680 blocks, 2 tiles each; same z per pair).
// ---------------------------------------------------------------------------
__global__ __launch_bounds__(512, 4) void gemm_vq4(
    const float* __restrict__ v,
    const float* __restrict__ q,
    const __bf16* __restrict__ Wt,     // weight table base (Wval | Wq | Wout)
    const float* __restrict__ b_val,
    const float* __restrict__ biasq,   // [384]
    __bf16* __restrict__ vpb,          // [B,8,N,32] bf16
    float* __restrict__ gqp)           // [B*Q,384] fp32
{
    // 2 x (64 rows x 128 k-half) bf16, XOR-swizzled in 8-elem blocks.
    __shared__ __bf16 As[2][64][128];

    const int tid  = threadIdx.x;
    const int lane = tid & 63;
    const int wave = tid >> 6;
    const int quad = lane >> 4;
    const int l16  = lane & 15;
    const int flat = blockIdx.x;

    const bool is_vp = (flat >= 384);
    int z = 0, tb, colep;
    const float* Arow;
    const __bf16* Wpan;
    if (is_vp) {
        const int bi = flat - 384;          // 0..679
        z  = bi / 170;
        tb = (bi - z * 170) * 128;          // 128 consecutive tokens
        Arow  = v + (size_t)z * NN * 256;
        Wpan  = Wt;
        colep = wave * 32;                  // v_p: wave owns 32 cols
    } else {
        const int g0 = flat * 2;            // even tile of 768
        const int slice = g0 >> 8;          // 0..2 (pairs never straddle)
        tb = (g0 & 255) * 64;
        Arow  = q;
        Wpan  = Wt + 65536 + (size_t)(slice * 128) * 256;
        colep = slice * 128 + wave * 16;    // global col base for epilogue
    }

    // ---- stage-issue / stage-write / compute helpers ----
    float4 a4[4];
    auto issue = [&](int ph) {
        const int tile = ph >> 1, h = ph & 1;
        #pragma unroll
        for (int c = 0; c < 4; ++c) {
            const int cid = c * 512 + tid;
            const int rr  = cid >> 5;              // 0..63
            const int kc  = (cid & 31) * 4;        // 0..124
            a4[c] = *(const float4*)(Arow + (size_t)(tb + tile * 64 + rr) * 256
                                      + h * 128 + kc);
        }
    };
    auto wr = [&](int ph) {
        const int buf = ph & 1;
        #pragma unroll
        for (int c = 0; c < 4; ++c) {
            const int cid = c * 512 + tid;
            const int rr  = cid >> 5;
            const int kc  = (cid & 31) * 4;
            bf16_4 w;
            w[0] = (__bf16)a4[c].x; w[1] = (__bf16)a4[c].y;
            w[2] = (__bf16)a4[c].z; w[3] = (__bf16)a4[c].w;
            const int col = ((((kc >> 3) ^ (rr & 7)) << 3) | (kc & 7));
            *(bf16_4*)&As[buf][rr][col] = w;
        }
    };

    // ---- prologue: loads(0) -> weights -> write(0) -> loads(1) -> barrier
    issue(0);

    bf16_8 wf0[8], wf1[8];
    #pragma unroll
    for (int kk = 0; kk < 8; ++kk) {
        wf0[kk] = *(const bf16_8*)(Wpan + (size_t)(colep % 384 - (is_vp ? 0 : (colep - wave * 16 - (colep >= 128 ? (colep >= 256 ? 256 : 128) : 0))) * 0 + 0) * 0
                                    + 0);  // placeholder removed below
    }
    // (clean weight loads — wave-local row index within the panel)
    {
        const int wrow0 = is_vp ? (wave * 32) : (wave * 16);
        #pragma unroll
        for (int kk = 0; kk < 8; ++kk) {
            wf0[kk] = *(const bf16_8*)(Wpan + (size_t)(wrow0 + l16) * 256 + kk * 32 + quad * 8);
            if (is_vp)
                wf1[kk] = *(const bf16_8*)(Wpan + (size_t)(wrow0 + 16 + l16) * 256 + kk * 32 + quad * 8);
        }
    }

    wr(0);
    issue(1);
    asm volatile("s_waitcnt lgkmcnt(0)" ::: "memory");
    __builtin_amdgcn_s_barrier();

    // ---- 4 phases: compute(p) with loads(p+1) in flight ----
    floatx4 acc0[4], acc1[4];
    #pragma unroll
    for (int p = 0; p < 4; ++p) {
        if ((p & 1) == 0) {
            #pragma unroll
            for (int it = 0; it < 4; ++it) { acc0[it] = (floatx4){0,0,0,0}; acc1[it] = (floatx4){0,0,0,0}; }
        }
        // compute: K-half (p&1) of tile (p>>1) from As[p&1]
        {
            const int buf = p & 1, h = p & 1;
            #pragma unroll
            for (int k2 = 0; k2 < 4; ++k2) {
                const int kk = h * 4 + k2;
                bf16_8 af[4];
                #pragma unroll
                for (int it = 0; it < 4; ++it)
                    af[it] = *(const bf16_8*)&As[buf][it * 16 + l16]
                                               [(((k2 * 4 + quad) ^ (l16 & 7)) << 3)];
                #pragma unroll
                for (int it = 0; it < 4; ++it) {
                    acc0[it] = __builtin_amdgcn_mfma_f32_16x16x32_bf16(wf0[kk], af[it], acc0[it], 0, 0, 0);
                    if (is_vp)
                        acc1[it] = __builtin_amdgcn_mfma_f32_16x16x32_bf16(wf1[kk], af[it], acc1[it], 0, 0, 0);
                }
            }
        }
        // epilogue at end of each tile (odd phase)
        if (p & 1) {
            const int tile = p >> 1;
            const int tok0 = tb + tile * 64;
            if (is_vp) {
                #pragma unroll
                for (int j = 0; j < 2; ++j) {
                    const int n0 = colep + j * 16 + quad * 4;
                    const float4 b4 = *(const float4*)(b_val + n0);
                    const int mh = n0 >> 5, dd = n0 & 31;
                    #pragma unroll
                    for (int it = 0; it < 4; ++it) {
                        const int token = tok0 + it * 16 + l16;
                        const floatx4 av = j ? acc1[it] : acc0[it];
                        bf16_4 ob;
                        ob[0] = (__bf16)(av[0] + b4.x);
                        ob[1] = (__bf16)(av[1] + b4.y);
                        ob[2] = (__bf16)(av[2] + b4.z);
                        ob[3] = (__bf16)(av[3] + b4.w);
                        *(bf16_4*)(vpb + (((size_t)z * 8 + mh) * NN + token) * 32 + dd) = ob;
                    }
                }
            } else {
                const int n0 = colep + quad * 4;
                const float4 b4 = *(const float4*)(biasq + n0);
                #pragma unroll
                for (int it = 0; it < 4; ++it) {
                    const int token = tok0 + it * 16 + l16;
                    float4 ot;
                    ot.x = acc0[it][0] + b4.x;
                    ot.y = acc0[it][1] + b4.y;
                    ot.z = acc0[it][2] + b4.z;
                    ot.w = acc0[it][3] + b4.w;
                    *(float4*)(gqp + (size_t)token * 384 + n0) = ot;
                }
            }
        }
        // stage next phase; issue phase-after-next; fence + raw barrier
        if (p < 3) {
            wr(p + 1);                 // waits (counted) only on a4's loads
            if (p < 2) issue(p + 2);   // stays in flight across the barrier
            asm volatile("s_waitcnt lgkmcnt(0)" ::: "memory");
            __builtin_amdgcn_s_barrier();
        }
    }
}

// ---------------------------------------------------------------------------
// Weight-stationary bf16 MFMA GEMM (out-projection; round-3 verbatim).
// ---------------------------------------------------------------------------
template<typename AT, int NCB, int MODE>
__global__ __launch_bounds__(512, 4) void gemm_ws(
    const AT* __restrict__ A,
    const __bf16* __restrict__ Wn,     // [NCTOT][256] bf16 (n-major)
    const float* __restrict__ bias,    // [NCTOT] fp32
    void* __restrict__ Cout,
    int tokens, int ldc)
{
    constexpr int F  = NCB / 8;
    constexpr int NJ = F / 16;

    const int z    = blockIdx.z;
    const int col0 = blockIdx.x * NCB;
    const AT* Ab   = A + (size_t)z * tokens * 256;
    const __bf16* Wb = Wn + (size_t)col0 * 256;

    __shared__ __bf16 As[64][256];

    const int tid  = threadIdx.x;
    const int lane = tid & 63;
    const int wave = tid >> 6;
    const int quad = lane >> 4;
    const int l16  = lane & 15;
    const int wave_f = wave * F;

    const int token0 = blockIdx.y * 64;
    if (sizeof(AT) == 4) {
        const float* Af = (const float*)Ab;
        #pragma unroll
        for (int c = 0; c < 8; ++c) {
            const int cid = c * 512 + tid;
            const int r   = cid >> 6;
            const int kc  = (cid & 63) * 4;
            const float4 av = *(const float4*)(Af + (size_t)(token0 + r) * 256 + kc);
            bf16_4 w;
            w[0] = (__bf16)av.x; w[1] = (__bf16)av.y;
            w[2] = (__bf16)av.z; w[3] = (__bf16)av.w;
            const int col = ((((kc >> 3) ^ (r & 7)) << 3) | (kc & 7));
            *(bf16_4*)&As[r][col] = w;
        }
    } else {
        const __bf16* Ah = (const __bf16*)Ab;
        #pragma unroll
        for (int c = 0; c < 4; ++c) {
            const int cid = c * 512 + tid;
            const int r   = cid >> 5;
            const int kc  = (cid & 31) * 8;
            const bf16_8 av = *(const bf16_8*)(Ah + (size_t)(token0 + r) * 256 + kc);
            const int col = (((kc >> 3) ^ (r & 7)) << 3);
            *(bf16_8*)&As[r][col] = av;
        }
    }

    bf16_8 wf[8][NJ];
    #pragma unroll
    for (int kk = 0; kk < 8; ++kk)
        #pragma unroll
        for (int j = 0; j < NJ; ++j)
            wf[kk][j] = *(const bf16_8*)(Wb + (size_t)(wave_f + j * 16 + l16) * 256
                                          + kk * 32 + quad * 8);
    __syncthreads();

    floatx4 acc[NJ][4] = {};
    #pragma unroll
    for (int kk = 0; kk < 8; ++kk) {
        bf16_8 af[4];
        #pragma unroll
        for (int it = 0; it < 4; ++it)
            af[it] = *(const bf16_8*)&As[it * 16 + l16]
                                       [(((kk * 4 + quad) ^ (l16 & 7)) << 3)];
        #pragma unroll
        for (int j = 0; j < NJ; ++j)
            #pragma unroll
            for (int it = 0; it < 4; ++it)
                acc[j][it] = __builtin_amdgcn_mfma_f32_16x16x32_bf16(wf[kk][j], af[it], acc[j][it], 0, 0, 0);
    }

    #pragma unroll
    for (int j = 0; j < NJ; ++j) {
        const int n0 = col0 + wave_f + j * 16 + quad * 4;
        const float4 b4 = *(const float4*)(bias + n0);
        #pragma unroll
        for (int it = 0; it < 4; ++it) {
            const int token = token0 + it * 16 + l16;
            const float v0 = acc[j][it][0] + b4.x;
            const float v1 = acc[j][it][1] + b4.y;
            const float v2 = acc[j][it][2] + b4.z;
            const float v3 = acc[j][it][3] + b4.w;
            if (MODE == 0) {
                float4 o; o.x = v0; o.y = v1; o.z = v2; o.w = v3;
                *(float4*)((float*)Cout + ((size_t)z * tokens + token) * ldc + n0) = o;
            } else {
                const int mh = n0 >> 5, dd = n0 & 31;
                bf16_4 ob;
                ob[0] = (__bf16)v0; ob[1] = (__bf16)v1; ob[2] = (__bf16)v2; ob[3] = (__bf16)v3;
                *(bf16_4*)((__bf16*)Cout + (((size_t)z * 8 + mh) * NN + token) * 32 + dd) = ob;
            }
        }
    }
}

// ---------------------------------------------------------------------------
// Fused softmax + bilinear sampling (round-3 verbatim): 16384 blocks x 512,
// one query per block (max gather TLP).
// ---------------------------------------------------------------------------
__device__ __forceinline__ float bflo(unsigned u) { return __uint_as_float(u << 16); }
__device__ __forceinline__ float bfhi(unsigned u) { return __uint_as_float(u & 0xffff0000u); }

__global__ __launch_bounds__(512) void sampler(
    const __bf16* __restrict__ vp,    // [B,8,N,32] bf16
    const float* __restrict__ gqp,    // [B*Q,384]
    const float* __restrict__ pref,   // [B*Q,4,2]
    __bf16* __restrict__ mid)         // [B*Q,256] bf16
{
    const int t    = threadIdx.x;
    const int m    = t >> 6;
    const int lane = t & 63;
    const int s    = lane >> 2;
    const int c    = lane & 3;
    const int l    = s >> 2;
    const int bq   = blockIdx.x;
    const int b    = bq >> 12;

    const int   Hi = 128 >> l;
    const float Hf = (float)Hi;
    const int   base = (l == 0) ? 0 : (l == 1) ? 16384 : (l == 2) ? 20480 : 21504;

    const float logit = gqp[(size_t)bq * 384 + m * 16 + s];
    const float e = __expf(logit);
    float sum = e;
    #pragma unroll
    for (int k = 4; k < 64; k <<= 1) sum += __shfl_xor(sum, k, 64);
    const float a = e * __builtin_amdgcn_rcpf(sum);

    const float2 off = *(const float2*)(gqp + (size_t)bq * 384 + 128 + (m * 16 + s) * 2);
    const float2 pr  = *(const float2*)(pref + (size_t)bq * 8 + l * 2);

    const float x = fmaf(pr.x, Hf, off.x - 0.5f);
    const float y = fmaf(pr.y, Hf, off.y - 0.5f);
    const float x0f = floorf(x), y0f = floorf(y);
    const float lx = x - x0f, ly = y - y0f;
    const int x0 = (int)x0f, y0 = (int)y0f;
    const int cx0 = min(max(x0, 0), Hi - 1), cx1 = min(max(x0 + 1, 0), Hi - 1);
    const int cy0 = min(max(y0, 0), Hi - 1), cy1 = min(max(y0 + 1, 0), Hi - 1);
    const bool vx0 = (x0 >= 0) && (x0 < Hi), vx1 = (x0 + 1 >= 0) && (x0 + 1 < Hi);
    const bool vy0 = (y0 >= 0) && (y0 < Hi), vy1 = (y0 + 1 >= 0) && (y0 + 1 < Hi);
    const float w00 = a * (1.f - lx) * (1.f - ly) * ((vx0 && vy0) ? 1.f : 0.f);
    const float w10 = a * lx * (1.f - ly) * ((vx1 && vy0) ? 1.f : 0.f);
    const float w01 = a * (1.f - lx) * ly * ((vx0 && vy1) ? 1.f : 0.f);
    const float w11 = a * lx * ly * ((vx1 && vy1) ? 1.f : 0.f);

    const __bf16* vbase = vp + ((size_t)b * 8 + m) * NN * 32;
    const uint4 u00 = *((const uint4*)(vbase + (size_t)(base + cy0 * Hi + cx0) * 32) + c);
    const uint4 u10 = *((const uint4*)(vbase + (size_t)(base + cy0 * Hi + cx1) * 32) + c);
    const uint4 u01 = *((const uint4*)(vbase + (size_t)(base + cy1 * Hi + cx0) * 32) + c);
    const uint4 u11 = *((const uint4*)(vbase + (size_t)(base + cy1 * Hi + cx1) * 32) + c);

    float f[8];
    f[0] = w00*bflo(u00.x) + w10*bflo(u10.x) + w01*bflo(u01.x) + w11*bflo(u11.x);
    f[1] = w00*bfhi(u00.x) + w10*bfhi(u10.x) + w01*bfhi(u01.x) + w11*bfhi(u11.x);
    f[2] = w00*bflo(u00.y) + w10*bflo(u10.y) + w01*bflo(u01.y) + w11*bflo(u11.y);
    f[3] = w00*bfhi(u00.y) + w10*bfhi(u10.y) + w01*bfhi(u01.y) + w11*bfhi(u11.y);
    f[4] = w00*bflo(u00.z) + w10*bflo(u10.z) + w01*bflo(u01.z) + w11*bflo(u11.z);
    f[5] = w00*bfhi(u00.z) + w10*bfhi(u10.z) + w01*bfhi(u01.z) + w11*bfhi(u11.z);
    f[6] = w00*bflo(u00.w) + w10*bflo(u10.w) + w01*bflo(u01.w) + w11*bflo(u11.w);
    f[7] = w00*bfhi(u00.w) + w10*bfhi(u10.w) + w01*bfhi(u01.w) + w11*bfhi(u11.w);

    const int b2 = (lane >> 2) & 1, b3 = (lane >> 3) & 1, b4i = (lane >> 4) & 1;
    #pragma unroll
    for (int j = 0; j < 4; ++j) {
        const float sel  = b2 ? f[j] : f[j + 4];
        const float recv = __shfl_xor(sel, 4, 64);
        f[j] = (b2 ? f[j + 4] : f[j]) + recv;
    }
    #pragma unroll
    for (int j = 0; j < 2; ++j) {
        const float sel  = b3 ? f[j] : f[j + 2];
        const float recv = __shfl_xor(sel, 8, 64);
        f[j] = (b3 ? f[j + 2] : f[j]) + recv;
    }
    {
        const float sel  = b4i ? f[0] : f[1];
        const float recv = __shfl_xor(sel, 16, 64);
        f[0] = (b4i ? f[1] : f[0]) + recv;
    }
    f[0] += __shfl_xor(f[0], 32, 64);

    if (!(lane & 32)) {
        const int chan = (c << 3) | (b2 << 2) | (b3 << 1) | b4i;
        mid[(size_t)bq * 256 + m * 32 + chan] = (__bf16)f[0];
    }
}

extern "C" void kernel_launch(void* const* d_in, const int* in_sizes, int n_in,
                              void* d_out, int out_size, void* d_ws, size_t ws_size,
                              hipStream_t stream) {
    const float* q      = (const float*)d_in[0];
    const float* p      = (const float*)d_in[1];
    const float* v      = (const float*)d_in[2];
    const float* W_off  = (const float*)d_in[5];
    const float* b_off  = (const float*)d_in[6];
    const float* W_attn = (const float*)d_in[7];
    const float* b_attn = (const float*)d_in[8];
    const float* W_val  = (const float*)d_in[9];
    const float* b_val  = (const float*)d_in[10];
    const float* W_out  = (const float*)d_in[11];
    const float* b_out  = (const float*)d_in[12];
    float* out = (float*)d_out;

    // Workspace layout (round-3):
    //   gqp   : float [16384*384]
    //   biasq : float [384]
    //   mid   : bf16  [16384*256]
    //   vpb   : bf16  [4*8*21760*32]
    //   Wt    : bf16  [229376]
    float*  gqp   = (float*)d_ws;
    float*  biasq = gqp + (size_t)16384 * 384;
    __bf16* mid   = (__bf16*)(biasq + 384);
    __bf16* vpb   = mid + (size_t)16384 * 256;
    __bf16* Wt    = vpb + (size_t)BB * 8 * NN * 32;
    __bf16* Wt_out = Wt + 163840;

    // 0) weights -> bf16 transposed
    prep_weights<<<898, 256, 0, stream>>>(W_val, W_attn, W_off, W_out, b_attn, b_off, Wt, biasq);

    // 1) pipelined v_p + q-proj: 384 q-proj + 680 v_p = 1064 blocks
    gemm_vq4<<<1064, 512, 0, stream>>>(v, q, Wt, b_val, biasq, vpb, gqp);

    // 2) softmax + bilinear sampling -> mid bf16 [B*Q,256]
    sampler<<<BB * QQ, 512, 0, stream>>>(vpb, gqp, p, mid);

    // 3) out = mid @ W_out + b_out  (2 slices -> 512 blocks)
    {
        dim3 grid(2, 256, 1);
        gemm_ws<__bf16, 128, 0><<<grid, 512, 0, stream>>>(mid, Wt_out, b_out, out, BB * QQ, 256);
    }
}

// Round 12
// 249.021 us; speedup vs baseline: 1.1894x; 1.1894x over previous
//
#include <hip/hip_runtime.h>
#include <cstddef>

// Problem constants (fixed by setup_inputs)
#define BB 4
#define QQ 4096
#define MM 8
#define NN 21760

typedef __bf16 bf16_8 __attribute__((ext_vector_type(8)));
typedef __bf16 bf16_4 __attribute__((ext_vector_type(4)));
typedef float  floatx4 __attribute__((ext_vector_type(4)));

// ---------------------------------------------------------------------------
// Weight prep: fp32 W[K][N] -> bf16 Wt[N][K]  (round-3 verified layout).
// Wt: Wval[256x256] | Wq[384x256] (attn 0..127 | off 128..383) | Wout[256x256]
// biasq[384] = [b_attn | b_off] fp32.
// ---------------------------------------------------------------------------
__global__ __launch_bounds__(256) void prep_weights(
    const float* __restrict__ Wv, const float* __restrict__ Wa,
    const float* __restrict__ Wo, const float* __restrict__ Wu,
    const float* __restrict__ ba, const float* __restrict__ bo,
    __bf16* __restrict__ Wt, float* __restrict__ biasq)
{
    const int gid = blockIdx.x * 256 + threadIdx.x;
    if (gid < 65536) {
        const int n = gid >> 8, k = gid & 255;
        Wt[gid] = (__bf16)Wv[k * 256 + n];
    } else if (gid < 163840) {
        const int o = gid - 65536;
        const int n = o >> 8, k = o & 255;
        Wt[gid] = (__bf16)(n < 128 ? Wa[k * 128 + n] : Wo[k * 256 + (n - 128)]);
    } else if (gid < 229376) {
        const int o = gid - 163840;
        const int n = o >> 8, k = o & 255;
        Wt[gid] = (__bf16)Wu[k * 256 + n];
    } else if (gid < 229760) {
        const int j = gid - 229376;
        biasq[j] = (j < 128) ? ba[j] : bo[j - 128];
    }
}

// ---------------------------------------------------------------------------
// Pipelined v_p + q-proj GEMM, register-budgeted for the toolchain's ~64-VGPR
// target (round-11's vq4 spilled ~60 regs to scratch: WRITE_SIZE 157 MB).
// Demand ~58: a4[4]=16 staged loads, wf[4]=16 (current K-half only, reloaded
// per phase from L2), acc[4]=16, addr ~10.  Sync skeleton = vq4 (verified
// correct): raw s_barrier + lgkmcnt(0)-only fences, so activation loads for
// phase p+2 stay IN FLIGHT across the barrier and land during compute(p).
// Each block: 128 tokens x 128 cols, 2 token-tiles x 2 K-halves = 4 phases,
// double-buffered As[2][64][128] (32 KB).
// Blocks 0..383   : q-proj (pair of 64-token tiles; slice = cols/128)
// Blocks 384..1743: v_p (4z x 170 token-groups x 2 col-halves)
// ---------------------------------------------------------------------------
__global__ __launch_bounds__(512, 4) void gemm_vq6(
    const float* __restrict__ v,
    const float* __restrict__ q,
    const __bf16* __restrict__ Wt,     // weight table base (Wval | Wq | Wout)
    const float* __restrict__ b_val,
    const float* __restrict__ biasq,   // [384]
    __bf16* __restrict__ vpb,          // [B,8,N,32] bf16
    float* __restrict__ gqp)           // [B*Q,384] fp32
{
    __shared__ __bf16 As[2][64][128];

    const int tid  = threadIdx.x;
    const int lane = tid & 63;
    const int wave = tid >> 6;
    const int quad = lane >> 4;
    const int l16  = lane & 15;
    const int flat = blockIdx.x;

    const bool is_vp = (flat >= 384);
    int z = 0, tb, colep;
    const float* Arow;
    const __bf16* Wpan;
    if (is_vp) {
        const int bi   = flat - 384;        // 0..1359
        const int ch   = bi & 1;            // col half 0/1
        const int rest = bi >> 1;           // 0..679
        z  = rest / 170;
        tb = (rest - z * 170) * 128;
        Arow  = v + (size_t)z * NN * 256;
        Wpan  = Wt + (size_t)(ch * 128) * 256;
        colep = ch * 128 + wave * 16;       // within 256-col v_p output
    } else {
        const int g0 = flat * 2;            // even tile of 768
        const int slice = g0 >> 8;          // 0..2 (pairs never straddle)
        tb = (g0 & 255) * 64;
        Arow  = q;
        Wpan  = Wt + 65536 + (size_t)(slice * 128) * 256;
        colep = slice * 128 + wave * 16;    // within 384-col gqp
    }
    const int wrow = wave * 16 + l16;       // weight row within the panel

    // ---- staging helpers (ph: tile = ph>>1, K-half = ph&1) ----
    float4 a4[4];
    auto issue = [&](int ph) {
        const int tile = ph >> 1, h = ph & 1;
        #pragma unroll
        for (int c = 0; c < 4; ++c) {
            const int cid = c * 512 + tid;
            const int rr  = cid >> 5;              // 0..63
            const int kc  = (cid & 31) * 4;        // 0..124
            a4[c] = *(const float4*)(Arow + (size_t)(tb + tile * 64 + rr) * 256
                                      + h * 128 + kc);
        }
    };
    auto wr = [&](int ph) {
        const int buf = ph & 1;
        #pragma unroll
        for (int c = 0; c < 4; ++c) {
            const int cid = c * 512 + tid;
            const int rr  = cid >> 5;
            const int kc  = (cid & 31) * 4;
            bf16_4 w;
            w[0] = (__bf16)a4[c].x; w[1] = (__bf16)a4[c].y;
            w[2] = (__bf16)a4[c].z; w[3] = (__bf16)a4[c].w;
            const int col = ((((kc >> 3) ^ (rr & 7)) << 3) | (kc & 7));
            *(bf16_4*)&As[buf][rr][col] = w;
        }
    };

    // ---- prologue: loads(0) -> write(0) -> loads(1) -> fence + barrier ----
    issue(0);
    wr(0);
    issue(1);
    asm volatile("s_waitcnt lgkmcnt(0)" ::: "memory");
    __builtin_amdgcn_s_barrier();

    // ---- 4 phases: compute(p) with loads(p+1) already in flight ----
    floatx4 acc[4];
    #pragma unroll
    for (int p = 0; p < 4; ++p) {
        const int h = p & 1;

        // this K-half's weight frags (L2-hot, 4 x 16B)
        bf16_8 wfp[4];
        #pragma unroll
        for (int k2 = 0; k2 < 4; ++k2)
            wfp[k2] = *(const bf16_8*)(Wpan + (size_t)wrow * 256
                                        + (h * 4 + k2) * 32 + quad * 8);

        if (h == 0) {
            #pragma unroll
            for (int it = 0; it < 4; ++it) acc[it] = (floatx4){0, 0, 0, 0};
        }

        #pragma unroll
        for (int k2 = 0; k2 < 4; ++k2) {
            bf16_8 af[4];
            #pragma unroll
            for (int it = 0; it < 4; ++it)
                af[it] = *(const bf16_8*)&As[p & 1][it * 16 + l16]
                                           [(((k2 * 4 + quad) ^ (l16 & 7)) << 3)];
            #pragma unroll
            for (int it = 0; it < 4; ++it)
                acc[it] = __builtin_amdgcn_mfma_f32_16x16x32_bf16(wfp[k2], af[it], acc[it], 0, 0, 0);
        }

        // epilogue at end of each tile (odd phase)
        if (h) {
            const int tok0 = tb + (p >> 1) * 64;
            if (is_vp) {
                const int n0 = colep + quad * 4;
                const float4 b4 = *(const float4*)(b_val + n0);
                const int mh = n0 >> 5, dd = n0 & 31;
                #pragma unroll
                for (int it = 0; it < 4; ++it) {
                    const int token = tok0 + it * 16 + l16;
                    bf16_4 ob;
                    ob[0] = (__bf16)(acc[it][0] + b4.x);
                    ob[1] = (__bf16)(acc[it][1] + b4.y);
                    ob[2] = (__bf16)(acc[it][2] + b4.z);
                    ob[3] = (__bf16)(acc[it][3] + b4.w);
                    *(bf16_4*)(vpb + (((size_t)z * 8 + mh) * NN + token) * 32 + dd) = ob;
                }
            } else {
                const int n0 = colep + quad * 4;
                const float4 b4 = *(const float4*)(biasq + n0);
                #pragma unroll
                for (int it = 0; it < 4; ++it) {
                    const int token = tok0 + it * 16 + l16;
                    float4 ot;
                    ot.x = acc[it][0] + b4.x;
                    ot.y = acc[it][1] + b4.y;
                    ot.z = acc[it][2] + b4.z;
                    ot.w = acc[it][3] + b4.w;
                    *(float4*)(gqp + (size_t)token * 384 + n0) = ot;
                }
            }
        }

        // stage next phase; issue phase-after-next; fence + raw barrier
        if (p < 3) {
            wr(p + 1);                 // waits (counted) only on a4's loads
            if (p < 2) issue(p + 2);   // stays in flight across the barrier
            asm volatile("s_waitcnt lgkmcnt(0)" ::: "memory");
            __builtin_amdgcn_s_barrier();
        }
    }
}

// ---------------------------------------------------------------------------
// Weight-stationary bf16 MFMA GEMM (out-projection; round-3 verbatim).
// ---------------------------------------------------------------------------
template<typename AT, int NCB, int MODE>
__global__ __launch_bounds__(512, 4) void gemm_ws(
    const AT* __restrict__ A,
    const __bf16* __restrict__ Wn,     // [NCTOT][256] bf16 (n-major)
    const float* __restrict__ bias,    // [NCTOT] fp32
    void* __restrict__ Cout,
    int tokens, int ldc)
{
    constexpr int F  = NCB / 8;
    constexpr int NJ = F / 16;

    const int z    = blockIdx.z;
    const int col0 = blockIdx.x * NCB;
    const AT* Ab   = A + (size_t)z * tokens * 256;
    const __bf16* Wb = Wn + (size_t)col0 * 256;

    __shared__ __bf16 As[64][256];

    const int tid  = threadIdx.x;
    const int lane = tid & 63;
    const int wave = tid >> 6;
    const int quad = lane >> 4;
    const int l16  = lane & 15;
    const int wave_f = wave * F;

    const int token0 = blockIdx.y * 64;
    if (sizeof(AT) == 4) {
        const float* Af = (const float*)Ab;
        #pragma unroll
        for (int c = 0; c < 8; ++c) {
            const int cid = c * 512 + tid;
            const int r   = cid >> 6;
            const int kc  = (cid & 63) * 4;
            const float4 av = *(const float4*)(Af + (size_t)(token0 + r) * 256 + kc);
            bf16_4 w;
            w[0] = (__bf16)av.x; w[1] = (__bf16)av.y;
            w[2] = (__bf16)av.z; w[3] = (__bf16)av.w;
            const int col = ((((kc >> 3) ^ (r & 7)) << 3) | (kc & 7));
            *(bf16_4*)&As[r][col] = w;
        }
    } else {
        const __bf16* Ah = (const __bf16*)Ab;
        #pragma unroll
        for (int c = 0; c < 4; ++c) {
            const int cid = c * 512 + tid;
            const int r   = cid >> 5;
            const int kc  = (cid & 31) * 8;
            const bf16_8 av = *(const bf16_8*)(Ah + (size_t)(token0 + r) * 256 + kc);
            const int col = (((kc >> 3) ^ (r & 7)) << 3);
            *(bf16_8*)&As[r][col] = av;
        }
    }

    bf16_8 wf[8][NJ];
    #pragma unroll
    for (int kk = 0; kk < 8; ++kk)
        #pragma unroll
        for (int j = 0; j < NJ; ++j)
            wf[kk][j] = *(const bf16_8*)(Wb + (size_t)(wave_f + j * 16 + l16) * 256
                                          + kk * 32 + quad * 8);
    __syncthreads();

    floatx4 acc[NJ][4] = {};
    #pragma unroll
    for (int kk = 0; kk < 8; ++kk) {
        bf16_8 af[4];
        #pragma unroll
        for (int it = 0; it < 4; ++it)
            af[it] = *(const bf16_8*)&As[it * 16 + l16]
                                       [(((kk * 4 + quad) ^ (l16 & 7)) << 3)];
        #pragma unroll
        for (int j = 0; j < NJ; ++j)
            #pragma unroll
            for (int it = 0; it < 4; ++it)
                acc[j][it] = __builtin_amdgcn_mfma_f32_16x16x32_bf16(wf[kk][j], af[it], acc[j][it], 0, 0, 0);
    }

    #pragma unroll
    for (int j = 0; j < NJ; ++j) {
        const int n0 = col0 + wave_f + j * 16 + quad * 4;
        const float4 b4 = *(const float4*)(bias + n0);
        #pragma unroll
        for (int it = 0; it < 4; ++it) {
            const int token = token0 + it * 16 + l16;
            const float v0 = acc[j][it][0] + b4.x;
            const float v1 = acc[j][it][1] + b4.y;
            const float v2 = acc[j][it][2] + b4.z;
            const float v3 = acc[j][it][3] + b4.w;
            if (MODE == 0) {
                float4 o; o.x = v0; o.y = v1; o.z = v2; o.w = v3;
                *(float4*)((float*)Cout + ((size_t)z * tokens + token) * ldc + n0) = o;
            } else {
                const int mh = n0 >> 5, dd = n0 & 31;
                bf16_4 ob;
                ob[0] = (__bf16)v0; ob[1] = (__bf16)v1; ob[2] = (__bf16)v2; ob[3] = (__bf16)v3;
                *(bf16_4*)((__bf16*)Cout + (((size_t)z * 8 + mh) * NN + token) * 32 + dd) = ob;
            }
        }
    }
}

// ---------------------------------------------------------------------------
// Fused softmax + bilinear sampling (round-3 verbatim): 16384 blocks x 512,
// one query per block (max gather TLP).
// ---------------------------------------------------------------------------
__device__ __forceinline__ float bflo(unsigned u) { return __uint_as_float(u << 16); }
__device__ __forceinline__ float bfhi(unsigned u) { return __uint_as_float(u & 0xffff0000u); }

__global__ __launch_bounds__(512) void sampler(
    const __bf16* __restrict__ vp,    // [B,8,N,32] bf16
    const float* __restrict__ gqp,    // [B*Q,384]
    const float* __restrict__ pref,   // [B*Q,4,2]
    __bf16* __restrict__ mid)         // [B*Q,256] bf16
{
    const int t    = threadIdx.x;
    const int m    = t >> 6;
    const int lane = t & 63;
    const int s    = lane >> 2;
    const int c    = lane & 3;
    const int l    = s >> 2;
    const int bq   = blockIdx.x;
    const int b    = bq >> 12;

    const int   Hi = 128 >> l;
    const float Hf = (float)Hi;
    const int   base = (l == 0) ? 0 : (l == 1) ? 16384 : (l == 2) ? 20480 : 21504;

    const float logit = gqp[(size_t)bq * 384 + m * 16 + s];
    const float e = __expf(logit);
    float sum = e;
    #pragma unroll
    for (int k = 4; k < 64; k <<= 1) sum += __shfl_xor(sum, k, 64);
    const float a = e * __builtin_amdgcn_rcpf(sum);

    const float2 off = *(const float2*)(gqp + (size_t)bq * 384 + 128 + (m * 16 + s) * 2);
    const float2 pr  = *(const float2*)(pref + (size_t)bq * 8 + l * 2);

    const float x = fmaf(pr.x, Hf, off.x - 0.5f);
    const float y = fmaf(pr.y, Hf, off.y - 0.5f);
    const float x0f = floorf(x), y0f = floorf(y);
    const float lx = x - x0f, ly = y - y0f;
    const int x0 = (int)x0f, y0 = (int)y0f;
    const int cx0 = min(max(x0, 0), Hi - 1), cx1 = min(max(x0 + 1, 0), Hi - 1);
    const int cy0 = min(max(y0, 0), Hi - 1), cy1 = min(max(y0 + 1, 0), Hi - 1);
    const bool vx0 = (x0 >= 0) && (x0 < Hi), vx1 = (x0 + 1 >= 0) && (x0 + 1 < Hi);
    const bool vy0 = (y0 >= 0) && (y0 < Hi), vy1 = (y0 + 1 >= 0) && (y0 + 1 < Hi);
    const float w00 = a * (1.f - lx) * (1.f - ly) * ((vx0 && vy0) ? 1.f : 0.f);
    const float w10 = a * lx * (1.f - ly) * ((vx1 && vy0) ? 1.f : 0.f);
    const float w01 = a * (1.f - lx) * ly * ((vx0 && vy1) ? 1.f : 0.f);
    const float w11 = a * lx * ly * ((vx1 && vy1) ? 1.f : 0.f);

    const __bf16* vbase = vp + ((size_t)b * 8 + m) * NN * 32;
    const uint4 u00 = *((const uint4*)(vbase + (size_t)(base + cy0 * Hi + cx0) * 32) + c);
    const uint4 u10 = *((const uint4*)(vbase + (size_t)(base + cy0 * Hi + cx1) * 32) + c);
    const uint4 u01 = *((const uint4*)(vbase + (size_t)(base + cy1 * Hi + cx0) * 32) + c);
    const uint4 u11 = *((const uint4*)(vbase + (size_t)(base + cy1 * Hi + cx1) * 32) + c);

    float f[8];
    f[0] = w00*bflo(u00.x) + w10*bflo(u10.x) + w01*bflo(u01.x) + w11*bflo(u11.x);
    f[1] = w00*bfhi(u00.x) + w10*bfhi(u10.x) + w01*bfhi(u01.x) + w11*bfhi(u11.x);
    f[2] = w00*bflo(u00.y) + w10*bflo(u10.y) + w01*bflo(u01.y) + w11*bflo(u11.y);
    f[3] = w00*bfhi(u00.y) + w10*bfhi(u10.y) + w01*bfhi(u01.y) + w11*bfhi(u11.y);
    f[4] = w00*bflo(u00.z) + w10*bflo(u10.z) + w01*bflo(u01.z) + w11*bflo(u11.z);
    f[5] = w00*bfhi(u00.z) + w10*bfhi(u10.z) + w01*bfhi(u01.z) + w11*bfhi(u11.z);
    f[6] = w00*bflo(u00.w) + w10*bflo(u10.w) + w01*bflo(u01.w) + w11*bflo(u11.w);
    f[7] = w00*bfhi(u00.w) + w10*bfhi(u10.w) + w01*bfhi(u01.w) + w11*bfhi(u11.w);

    const int b2 = (lane >> 2) & 1, b3 = (lane >> 3) & 1, b4i = (lane >> 4) & 1;
    #pragma unroll
    for (int j = 0; j < 4; ++j) {
        const float sel  = b2 ? f[j] : f[j + 4];
        const float recv = __shfl_xor(sel, 4, 64);
        f[j] = (b2 ? f[j + 4] : f[j]) + recv;
    }
    #pragma unroll
    for (int j = 0; j < 2; ++j) {
        const float sel  = b3 ? f[j] : f[j + 2];
        const float recv = __shfl_xor(sel, 8, 64);
        f[j] = (b3 ? f[j + 2] : f[j]) + recv;
    }
    {
        const float sel  = b4i ? f[0] : f[1];
        const float recv = __shfl_xor(sel, 16, 64);
        f[0] = (b4i ? f[1] : f[0]) + recv;
    }
    f[0] += __shfl_xor(f[0], 32, 64);

    if (!(lane & 32)) {
        const int chan = (c << 3) | (b2 << 2) | (b3 << 1) | b4i;
        mid[(size_t)bq * 256 + m * 32 + chan] = (__bf16)f[0];
    }
}

extern "C" void kernel_launch(void* const* d_in, const int* in_sizes, int n_in,
                              void* d_out, int out_size, void* d_ws, size_t ws_size,
                              hipStream_t stream) {
    const float* q      = (const float*)d_in[0];
    const float* p      = (const float*)d_in[1];
    const float* v      = (const float*)d_in[2];
    const float* W_off  = (const float*)d_in[5];
    const float* b_off  = (const float*)d_in[6];
    const float* W_attn = (const float*)d_in[7];
    const float* b_attn = (const float*)d_in[8];
    const float* W_val  = (const float*)d_in[9];
    const float* b_val  = (const float*)d_in[10];
    const float* W_out  = (const float*)d_in[11];
    const float* b_out  = (const float*)d_in[12];
    float* out = (float*)d_out;

    // Workspace layout (round-3):
    //   gqp   : float [16384*384]
    //   biasq : float [384]
    //   mid   : bf16  [16384*256]
    //   vpb   : bf16  [4*8*21760*32]
    //   Wt    : bf16  [229376]
    float*  gqp   = (float*)d_ws;
    float*  biasq = gqp + (size_t)16384 * 384;
    __bf16* mid   = (__bf16*)(biasq + 384);
    __bf16* vpb   = mid + (size_t)16384 * 256;
    __bf16* Wt    = vpb + (size_t)BB * 8 * NN * 32;
    __bf16* Wt_out = Wt + 163840;

    // 0) weights -> bf16 transposed
    prep_weights<<<898, 256, 0, stream>>>(W_val, W_attn, W_off, W_out, b_attn, b_off, Wt, biasq);

    // 1) pipelined v_p + q-proj: 384 q-proj + 1360 v_p = 1744 blocks
    gemm_vq6<<<1744, 512, 0, stream>>>(v, q, Wt, b_val, biasq, vpb, gqp);

    // 2) softmax + bilinear sampling -> mid bf16 [B*Q,256]
    sampler<<<BB * QQ, 512, 0, stream>>>(vpb, gqp, p, mid);

    // 3) out = mid @ W_out + b_out  (2 slices -> 512 blocks)
    {
        dim3 grid(2, 256, 1);
        gemm_ws<__bf16, 128, 0><<<grid, 512, 0, stream>>>(mid, Wt_out, b_out, out, BB * QQ, 256);
    }
}